// Round 4
// baseline (131.987 us; speedup 1.0000x reference)
//
#include <hip/hip_runtime.h>

constexpr int kC = 147, kH = 64, kBPM = 32;

typedef __attribute__((ext_vector_type(8)))  short bf16x8;   // MFMA A/B frag
typedef __attribute__((ext_vector_type(4)))  float f32x4;    // 16x16 C/D frag
typedef __attribute__((ext_vector_type(16))) float f32x16;   // 32x32 C/D frag
typedef __attribute__((ext_vector_type(2)))  unsigned u32x2;
typedef __attribute__((ext_vector_type(4)))  unsigned u32x4;

__device__ __forceinline__ short f2bf(float f) {             // RNE float->bf16
    unsigned u = __builtin_bit_cast(unsigned, f);
    u += 0x7fffu + ((u >> 16) & 1u);
    return (short)(u >> 16);
}
// Packed RNE f32x2 -> bf16x2 (single VALU op; bit-identical to f2bf pairs).
__device__ __forceinline__ unsigned cvt_pk(float lo, float hi) {
    unsigned r;
    asm("v_cvt_pk_bf16_f32 %0, %1, %2" : "=v"(r) : "v"(lo), "v"(hi));
    return r;
}
#define MFMA16(a,b,c) __builtin_amdgcn_mfma_f32_16x16x32_bf16((a),(b),(c),0,0,0)
#define MFMA32(a,b,c) __builtin_amdgcn_mfma_f32_32x32x16_bf16((a),(b),(c),0,0,0)

// Softmax in base 2: Wq and q-bias pre-scaled by 0.25*log2(e); P = 2^s.
#if __has_builtin(__builtin_amdgcn_exp2f)
  #define EXP2(x) __builtin_amdgcn_exp2f(x)
#else
  #define EXP2(x) __expf((x) * 0.6931471805599453f)   // exact: e^(x ln2) = 2^x
#endif
constexpr float kQScale = 0.25f * 1.4426950408889634f;

// LDS strides (shorts); all rows 16B-aligned.
constexpr int QS  = 72;    // qs/ks row stride
constexpr int VS  = 264;   // vt row stride
constexpr int WSS = 168;   // Ws qkv: [c][k], k padded to 160 (XOR-swizzled k)
constexpr int WOS = 72;    // Ws oproj: [n][k], k=64 (XOR-swizzled k)

// LDS write-out of a prefetched W (values already scaled at load time).
// Thread map matches the coalesced load map: c = i&63, k-pair = i>>6.
__device__ __forceinline__ void stage_w_regs(const float* wr /*10*/,
                                             short* Ws, int tid) {
    #pragma unroll
    for (int it = 0; it < 5; ++it) {
        const int i = it * 1024 + tid;          // 5120 = 64c x 80 k-pairs
        const int c = i & 63, k = (i >> 6) * 2;
        *(unsigned*)&Ws[c * WSS + (k ^ (((c >> 3) & 3) << 3))]
            = cvt_pk(wr[2*it], wr[2*it + 1]);
    }
}

// One block per batch: 1024 threads = 16 waves = 4 waves/SIMD; LDS ~128 KB.
__global__ __launch_bounds__(1024, 4) void fused_kernel(
    const float* __restrict__ pose, const float* __restrict__ bpm_emb,
    const float* __restrict__ Wq, const float* __restrict__ bq,
    const float* __restrict__ Wk, const float* __restrict__ bk,
    const float* __restrict__ Wv, const float* __restrict__ bv,
    const float* __restrict__ Wb, const float* __restrict__ bb,
    const float* __restrict__ Wo, const float* __restrict__ bo,
    float* __restrict__ out)
{
    __shared__ __align__(16) short qs[256 * QS];    // q, later attn-out X  36.9 KB
    __shared__ __align__(16) short ks_[256 * QS];   // k (+bpm bias)        36.9 KB
    __shared__ __align__(16) short vt[kH * VS];     // V^T: [h*16+d][j]     33.8 KB
    __shared__ __align__(16) short Ws[11520];       // Wqkv (10752) / Wo    23.0 KB
    __shared__ float bias_s[192];

    const int tid = threadIdx.x;
    const int w = tid >> 6, lane = tid & 63;
    const int ll = lane & 15, lq = lane >> 4;
    const int lm = lane & 31, lh = lane >> 5;
    const int b = blockIdx.x;
    const size_t pbase = (size_t)b * 256 * kC;

    // ---- T14 async-stage: ALL weights -> regs in prologue (coalesced).
    // Post-barrier stages become pure LDS writes; L2 latency hides here.
    float wq_r[10], wk_r[10], wv_r[10], wo_r[10];
    #pragma unroll
    for (int it = 0; it < 5; ++it) {
        const int i = it * 1024 + tid;
        const int c = i & 63, k = (i >> 6) * 2;
        const bool b0 = k < kC, b1 = k + 1 < kC;
        wq_r[2*it]   = b0 ? Wq[k * kH + c] * kQScale : 0.f;
        wq_r[2*it+1] = b1 ? Wq[(k + 1) * kH + c] * kQScale : 0.f;
        wk_r[2*it]   = b0 ? Wk[k * kH + c] : 0.f;
        wk_r[2*it+1] = b1 ? Wk[(k + 1) * kH + c] : 0.f;
        wv_r[2*it]   = b0 ? Wv[k * kH + c] : 0.f;
        wv_r[2*it+1] = b1 ? Wv[(k + 1) * kH + c] : 0.f;
        const int n = i % 160, ko = (i / 160) * 2;  // oproj map: [n][k]
        wo_r[2*it]   = (n < kC) ? Wo[ko * kC + n] : 0.f;
        wo_r[2*it+1] = (n < kC) ? Wo[(ko + 1) * kC + n] : 0.f;
    }

    // ---- pose B-frags (HBM loads in flight early) ----
    bf16x8 pf[5];
    {
        const int row = w * 16 + ll;
        const float* prow = pose + pbase + (size_t)row * kC;
        #pragma unroll
        for (int ksp = 0; ksp < 5; ++ksp) {
            const int c0 = ksp * 32 + lq * 8;
            float v[8];
            if (c0 + 8 <= kC) {
                const float4 f0 = *(const float4*)(prow + c0);
                const float4 f1 = *(const float4*)(prow + c0 + 4);
                v[0]=f0.x; v[1]=f0.y; v[2]=f0.z; v[3]=f0.w;
                v[4]=f1.x; v[5]=f1.y; v[6]=f1.z; v[7]=f1.w;
            } else {
                #pragma unroll
                for (int e = 0; e < 8; ++e) v[e] = (c0 + e < kC) ? prow[c0 + e] : 0.f;
            }
            const u32x4 t = { cvt_pk(v[0], v[1]), cvt_pk(v[2], v[3]),
                              cvt_pk(v[4], v[5]), cvt_pk(v[6], v[7]) };
            pf[ksp] = __builtin_bit_cast(bf16x8, t);
        }
    }
    // ---- combined biases (q-bias pre-scaled by kQScale) ----
    if (tid < 192) {
        const int m = tid >> 6, c = tid & 63;
        float a = ((m == 0) ? bq : (m == 1) ? bk : bv)[c];
        if (m == 1) {
            a += bb[c];
            #pragma unroll
            for (int k2 = 0; k2 < kBPM; ++k2)
                a = fmaf(bpm_emb[b * kBPM + k2], Wb[k2 * kH + c], a);
        }
        if (m == 0) a *= kQScale;
        bias_s[tid] = a;
    }
    // ---- stage Wq (already scaled in regs) ----
    stage_w_regs(wq_r, Ws, tid);
    __syncthreads();

    // ================= QKV: wave = 16 pose rows, A = W^T (M=64 cols) =======
    #pragma unroll
    for (int m = 0; m < 3; ++m) {
        f32x4 acc[4];
        #pragma unroll
        for (int mt = 0; mt < 4; ++mt) acc[mt] = (f32x4){0.f,0.f,0.f,0.f};
        #pragma unroll
        for (int ksp = 0; ksp < 5; ++ksp)
            #pragma unroll
            for (int mt = 0; mt < 4; ++mt) {
                const int c = mt * 16 + ll;
                const int key = ((c >> 3) & 3) << 3;
                const bf16x8 wf = *(const bf16x8*)(Ws + c * WSS + ((ksp*32 + lq*8) ^ key));
                acc[mt] = MFMA16(wf, pf[ksp], acc[mt]);
            }
        __syncthreads();                       // all waves done reading Ws
        if (m == 0)      stage_w_regs(wk_r, Ws, tid);   // pure LDS writes
        else if (m == 1) stage_w_regs(wv_r, Ws, tid);
        else {                                  // m==2: stage Wo^T[n][k] now
            #pragma unroll
            for (int it = 0; it < 5; ++it) {
                const int i = it * 1024 + tid;  // 5120 = 160n x 32 k-pairs
                const int n = i % 160, k = (i / 160) * 2;
                *(unsigned*)&Ws[n * WOS + (k ^ (((n >> 3) & 3) << 3))]
                    = cvt_pk(wo_r[2*it], wo_r[2*it + 1]);
            }
        }
        // epilogue: D row = out-col mt*16+4lq+r, D col = pose-row w*16+ll
        const int row = w * 16 + ll;
        #pragma unroll
        for (int mt = 0; mt < 4; ++mt) {
            const int c0 = mt * 16 + 4 * lq;
            const float4 bv4 = *(const float4*)&bias_s[m * kH + c0];
            if (m < 2) {
                const u32x2 pk = { cvt_pk(acc[mt][0] + bv4.x, acc[mt][1] + bv4.y),
                                   cvt_pk(acc[mt][2] + bv4.z, acc[mt][3] + bv4.w) };
                *(u32x2*)((m == 0 ? qs : ks_) + row * QS + c0) = pk;
            } else {                            // V stored transposed: vt[c][row]
                vt[(c0 + 0) * VS + row] = f2bf(acc[mt][0] + bv4.x);
                vt[(c0 + 1) * VS + row] = f2bf(acc[mt][1] + bv4.y);
                vt[(c0 + 2) * VS + row] = f2bf(acc[mt][2] + bv4.z);
                vt[(c0 + 3) * VS + row] = f2bf(acc[mt][3] + bv4.w);
            }
        }
        __syncthreads();
    }

    // ================= attention: wave = (head, q-quarter of 64) ===========
    // Swapped QK^T (lane = q) + permlane half-exchange keeps P entirely in
    // registers; PV = 32x32x16 MFMA with B=P (col=q=lane). No P LDS at all.
    const int h = w & 3;
    const int q0 = (w >> 2) * 64;
    bf16x8 qf[2];                              // B-frags (read own q region)
    #pragma unroll
    for (int s32 = 0; s32 < 2; ++s32)
        qf[s32] = *(const bf16x8*)(qs + (q0 + s32*32 + lm) * QS + h*16 + lh*8);

    f32x16 oacc[2];                            // D: col=q=lm, row=d (regs 0-7 valid)
    #pragma unroll
    for (int s32 = 0; s32 < 2; ++s32)
        oacc[s32] = (f32x16){0.f,0.f,0.f,0.f,0.f,0.f,0.f,0.f,
                             0.f,0.f,0.f,0.f,0.f,0.f,0.f,0.f};
    float lp[2] = {0.f, 0.f};
    const int vrow = h * 16 + (lm & 15);       // lanes 16-31 dup rows (bcast, free)
    const f32x16 z16 = {0.f,0.f,0.f,0.f,0.f,0.f,0.f,0.f,
                        0.f,0.f,0.f,0.f,0.f,0.f,0.f,0.f};

    #pragma unroll 2
    for (int jb = 0; jb < 8; ++jb) {
        const int j0 = jb * 32;
        const bf16x8 kf  = *(const bf16x8*)(ks_ + (j0 + lm) * QS + h*16 + lh*8);
        // A-frags for PV: lane holds V^T row d=lm&15, k=j (lh splits j-halves)
        const bf16x8 va0 = *(const bf16x8*)(vt + vrow * VS + j0 + lh*8);
        const bf16x8 va1 = *(const bf16x8*)(vt + vrow * VS + j0 + 16 + lh*8);
        #pragma unroll
        for (int s32 = 0; s32 < 2; ++s32) {
            const f32x16 s = MFMA32(kf, qf[s32], z16);   // S^T: col=q=lm, row=j
            float sum = 0.f;
            unsigned u[8];
            #pragma unroll
            for (int g = 0; g < 4; ++g) {                // j = r + 8g + 4lh
                const float p0 = EXP2(s[4*g + 0]);       // scale folded into Wq
                const float p1 = EXP2(s[4*g + 1]);
                const float p2 = EXP2(s[4*g + 2]);
                const float p3 = EXP2(s[4*g + 3]);
                sum += (p0 + p1) + (p2 + p3);
                u[2*g]   = cvt_pk(p0, p1);
                u[2*g+1] = cvt_pk(p2, p3);
            }
            lp[s32] += sum;
            // lane±32 half-exchange -> B-frags with k=j in order (T12):
            // (reg0,reg2)=swap(u0,u2), (reg1,reg3)=swap(u1,u3); same for j+16.
            unsigned a0 = u[0], a1 = u[1], b0 = u[2], b1 = u[3];
            asm("v_permlane32_swap_b32 %0, %1" : "+v"(a0), "+v"(b0));
            asm("v_permlane32_swap_b32 %0, %1" : "+v"(a1), "+v"(b1));
            unsigned c0 = u[4], c1 = u[5], d0 = u[6], d1 = u[7];
            asm("v_permlane32_swap_b32 %0, %1" : "+v"(c0), "+v"(d0));
            asm("v_permlane32_swap_b32 %0, %1" : "+v"(c1), "+v"(d1));
            const u32x4 pb0 = { a0, a1, b0, b1 };
            const u32x4 pb1 = { c0, c1, d0, d1 };
            oacc[s32] = MFMA32(va0, __builtin_bit_cast(bf16x8, pb0), oacc[s32]);
            oacc[s32] = MFMA32(va1, __builtin_bit_cast(bf16x8, pb1), oacc[s32]);
        }
    }
    // ---- normalize + X write (row-sum is lane-local now; no l_s) ----
    #pragma unroll
    for (int s32 = 0; s32 < 2; ++s32) {
        const float l2 = lp[s32] + __shfl_xor(lp[s32], 32);
        const float inv = 1.f / l2;
        const int row = q0 + s32 * 32 + lm;
        // oacc regs r=0..7 hold d = (r&3) + 8*(r>>2) + 4*lh
        const u32x2 pkA = { cvt_pk(oacc[s32][0] * inv, oacc[s32][1] * inv),
                            cvt_pk(oacc[s32][2] * inv, oacc[s32][3] * inv) };
        *(u32x2*)(qs + row * QS + h*16 + 4*lh) = pkA;
        const u32x2 pkB = { cvt_pk(oacc[s32][4] * inv, oacc[s32][5] * inv),
                            cvt_pk(oacc[s32][6] * inv, oacc[s32][7] * inv) };
        *(u32x2*)(qs + row * QS + h*16 + 8 + 4*lh) = pkB;
    }
    __syncthreads();                            // X complete; Wo already staged

    // ================= output projection: X[256x64] @ Wo + bo ==============
    bf16x8 xf[2];
    #pragma unroll
    for (int k2 = 0; k2 < 2; ++k2)
        xf[k2] = *(const bf16x8*)(qs + (w*16 + ll) * QS + k2*32 + lq*8);

    f32x4 po[10];
    #pragma unroll
    for (int mt = 0; mt < 10; ++mt) po[mt] = (f32x4){0.f,0.f,0.f,0.f};
    #pragma unroll
    for (int k2 = 0; k2 < 2; ++k2)
        #pragma unroll
        for (int mt = 0; mt < 10; ++mt) {
            const int n = mt * 16 + ll;
            const int key = ((n >> 3) & 3) << 3;
            const bf16x8 wf = *(const bf16x8*)(Ws + n * WOS + ((k2*32 + lq*8) ^ key));
            po[mt] = MFMA16(wf, xf[k2], po[mt]);
        }
    {
        const int row = w * 16 + ll;
        float* orow = out + ((size_t)b * 256 + row) * kC;
        #pragma unroll
        for (int mt = 0; mt < 10; ++mt) {
            const int c0 = mt * 16 + 4 * lq;
            if (mt < 9) {
                const float4 bv4 = *(const float4*)(bo + c0);
                float4 o;
                o.x = po[mt][0] + bv4.x; o.y = po[mt][1] + bv4.y;
                o.z = po[mt][2] + bv4.z; o.w = po[mt][3] + bv4.w;
                *(float4*)(orow + c0) = o;
            } else {
                #pragma unroll
                for (int r = 0; r < 4; ++r) {
                    const int c = c0 + r;
                    if (c < kC) orow[c] = po[mt][r] + bo[c];
                }
            }
        }
    }
}

extern "C" void kernel_launch(void* const* d_in, const int* in_sizes, int n_in,
                              void* d_out, int out_size, void* d_ws, size_t ws_size,
                              hipStream_t stream) {
    const float* pose    = (const float*)d_in[0];
    const float* bpm_emb = (const float*)d_in[1];
    const float* Wq = (const float*)d_in[2];  const float* bq = (const float*)d_in[3];
    const float* Wk = (const float*)d_in[4];  const float* bk = (const float*)d_in[5];
    const float* Wv = (const float*)d_in[6];  const float* bv = (const float*)d_in[7];
    const float* Wb = (const float*)d_in[8];  const float* bb = (const float*)d_in[9];
    const float* Wo = (const float*)d_in[10]; const float* bo = (const float*)d_in[11];
    float* out = (float*)d_out;

    fused_kernel<<<256, 1024, 0, stream>>>(
        pose, bpm_emb, Wq, bq, Wk, bk, Wv, bv, Wb, bb, Wo, bo, out);
}